// Round 6
// baseline (269.675 us; speedup 1.0000x reference)
//
#include <hip/hip_runtime.h>
#include <hip/hip_bf16.h>

typedef __attribute__((ext_vector_type(8))) short bf16x8;
typedef __attribute__((ext_vector_type(4))) float f32x4;
typedef unsigned short u16;
typedef unsigned int u32;

// ---- helpers ---------------------------------------------------------------

__device__ __forceinline__ u16 f2bf(float f) {
  union { float f; u32 u; } v; v.f = f;
  u32 r = v.u + 0x7FFFu + ((v.u >> 16) & 1u);   // round-to-nearest-even
  return (u16)(r >> 16);
}

__device__ __forceinline__ void gload_lds16(const u16* g, u16* l) {
  __builtin_amdgcn_global_load_lds(
      (const __attribute__((address_space(1))) u32*)(const void*)g,
      (__attribute__((address_space(3))) u32*)(void*)l, 16, 0, 0);
}

// ---- merged fp32 -> bf16 conversion (x + Wq + Wk + Wv in one launch) -------

__global__ __launch_bounds__(256) void cvt_all(const float* __restrict__ x,
                                               const float* __restrict__ wq,
                                               const float* __restrict__ wk,
                                               const float* __restrict__ wv,
                                               u16* __restrict__ xb,
                                               u16* __restrict__ wcat) {
  const int bid = blockIdx.x;
  const float* src; u16* dst; size_t base;
  if (bid < 4096) { src = x; dst = xb; base = (size_t)bid * 2048; }
  else {
    int w = bid - 4096, s = w >> 9;
    src = (s == 0) ? wq : ((s == 1) ? wk : wv);
    dst = wcat + (size_t)s * 1048576;
    base = (size_t)(w & 511) * 2048;
  }
  size_t i = base + (size_t)threadIdx.x * 8;
  const float4* p = (const float4*)(src + i);
  float4 a = p[0], b = p[1];
  union { u16 u[8]; uint4 v; } r;
  r.u[0] = f2bf(a.x); r.u[1] = f2bf(a.y); r.u[2] = f2bf(a.z); r.u[3] = f2bf(a.w);
  r.u[4] = f2bf(b.x); r.u[5] = f2bf(b.y); r.u[6] = f2bf(b.z); r.u[7] = f2bf(b.w);
  *(uint4*)(dst + i) = r.v;
}

// ---- 8-phase counted-vmcnt B^T GEMM (T3+T4+T5 port) ------------------------
// BM x 256 tile, 8 waves (2M x 4N; wave = BM/2 x 64), BK=64 split as 2 ks-
// slices of 32. LDS per buffer: A[2 ks][BM x 32] + B[2 ks][256 x 32]; two
// buffers (K-tile parity). 32-elem-K slots have 64 B row stride -> naturally
// bank-conflict-free for gload_lds writes AND ds_read_b128 frag reads.
// Per K-tile: 4 phases (ks, mh). Phase = { ds_read frags | stage ONE half-
// slot of tile t+1 -> s_barrier -> lgkmcnt(0) -> setprio(1) MT*4 MFMA
// setprio(0) -> [counted vmcnt at ks boundaries] -> s_barrier }.
// vmcnt ledger (per thread, BM=256: 2 loads/A-slot, 2/B-slot):
//   entering tile t: 4 outstanding (t.ks1 slots)
//   P0 +2 (A t+1.ks0) -> 6 ; P1 +2 (B t+1.ks0) -> 8 ; end-P1 vmcnt(4)
//     completes t.ks1, leaves t+1.ks0 in flight
//   P2 +2 -> 6 ; P3 +2 -> 8 ; end-P3 vmcnt(4) completes t+1.ks0.
// BM=128: A-slot is 1 load -> counts 3/4/6 -> vmcnt(3).
// Last tile stages nothing: end-P1 uses vmcnt(0) (drain).
// MODE 0: fused QKV projection (bias; V-blocks transposed via LDS).
// MODE 2: P = exp(QK^T/32) bf16 + row-sum atomics into lsum.
// MODE 3: O = (P * Vt^T) / l, fp32; batch folded into M.

template<int MODE, int BM>
__global__ __launch_bounds__(512, 2) void gemm8(
    const u16* __restrict__ A, const u16* __restrict__ B,
    const float* __restrict__ b0, const float* __restrict__ b1,
    const float* __restrict__ b2,
    void* __restrict__ o0, void* __restrict__ o1, void* __restrict__ o2,
    float* __restrict__ lsum, int lda, int ldb, int nkt,
    long Abat, long Bbat) {
  extern __shared__ u16 lds[];
  constexpr int MT = BM / 64;                 // m-tiles per phase
  constexpr int ASLOT = BM * 32;              // u16 per A ks-slot
  constexpr int BSLOT = 256 * 32;
  constexpr int BUFSZ = 2 * ASLOT + 2 * BSLOT;
  constexpr int ALD = BM / 128;               // gload_lds per thread per A slot

  const int tid = threadIdx.x;
  const int lane = tid & 63, wv = tid >> 6;
  const int lr = lane & 15, lg = lane >> 4;
  const int wm = wv >> 2, wn = wv & 3;
  const int bm = blockIdx.x * BM, bn = blockIdx.y * 256;
  const int bz = blockIdx.z;

  const u16* Ab; const u16* Bb;
  if constexpr (MODE == 3) { Ab = A; Bb = B + (size_t)Bbat * (bm >> 11); }
  else { Ab = A + (size_t)Abat * bz; Bb = B + (size_t)Bbat * bz; }

  f32x4 acc[2 * MT][4];
#pragma unroll
  for (int i = 0; i < 2 * MT; ++i)
#pragma unroll
    for (int j = 0; j < 4; ++j) acc[i][j] = (f32x4)0.0f;

  auto stageA = [&](int t1, int ks) {
    u16* base = lds + (t1 & 1) * BUFSZ + ks * ASLOT;
    const int k0 = t1 * 64 + ks * 32;
#pragma unroll
    for (int j = 0; j < ALD; ++j) {
      int id = j * 512 + tid, row = id >> 2, kg = id & 3;
      gload_lds16(Ab + (size_t)(bm + row) * lda + k0 + kg * 8, base + id * 8);
    }
  };
  auto stageB = [&](int t1, int ks) {
    u16* base = lds + (t1 & 1) * BUFSZ + 2 * ASLOT + ks * BSLOT;
    const int k0 = t1 * 64 + ks * 32;
#pragma unroll
    for (int j = 0; j < 2; ++j) {
      int id = j * 512 + tid, row = id >> 2, kg = id & 3;
      gload_lds16(Bb + (size_t)(bn + row) * ldb + k0 + kg * 8, base + id * 8);
    }
  };

  // prologue: stage tile 0 fully; complete ks0 slots, leave ks1 in flight
  stageA(0, 0); stageB(0, 0); stageA(0, 1); stageB(0, 1);
  if constexpr (BM == 256) asm volatile("s_waitcnt vmcnt(4)" ::: "memory");
  else                     asm volatile("s_waitcnt vmcnt(3)" ::: "memory");
  __builtin_amdgcn_s_barrier();

  for (int t = 0; t < nkt; ++t) {
    const bool stg = (t + 1 < nkt);
    const u16* Ab0 = lds + (t & 1) * BUFSZ;
    const u16* Bb0 = Ab0 + 2 * ASLOT;
    bf16x8 bfr[4];
#pragma unroll
    for (int ks = 0; ks < 2; ++ks) {
#pragma unroll
      for (int mh = 0; mh < 2; ++mh) {
        // --- ds-read frags ---
        if (mh == 0) {
#pragma unroll
          for (int nt = 0; nt < 4; ++nt) {
            int row = wn * 64 + nt * 16 + lr;
            bfr[nt] = *(const bf16x8*)(Bb0 + ks * BSLOT + row * 32 + lg * 8);
          }
        }
        bf16x8 afr[MT];
#pragma unroll
        for (int mt = 0; mt < MT; ++mt) {
          int row = wm * (BM / 2) + mh * (BM / 4) + mt * 16 + lr;
          afr[mt] = *(const bf16x8*)(Ab0 + ks * ASLOT + row * 32 + lg * 8);
        }
        // --- stage one half-slot of tile t+1 ---
        if (stg) {
          if (ks == 0 && mh == 0) stageA(t + 1, 0);
          else if (ks == 0 && mh == 1) stageB(t + 1, 0);
          else if (ks == 1 && mh == 0) stageA(t + 1, 1);
          else stageB(t + 1, 1);
        }
        __builtin_amdgcn_s_barrier();
        asm volatile("s_waitcnt lgkmcnt(0)" ::: "memory");
        __builtin_amdgcn_sched_barrier(0);
        __builtin_amdgcn_s_setprio(1);
#pragma unroll
        for (int mt = 0; mt < MT; ++mt)
#pragma unroll
          for (int nt = 0; nt < 4; ++nt)
            acc[mh * MT + mt][nt] = __builtin_amdgcn_mfma_f32_16x16x32_bf16(
                afr[mt], bfr[nt], acc[mh * MT + mt][nt], 0, 0, 0);
        __builtin_amdgcn_s_setprio(0);
        __builtin_amdgcn_sched_barrier(0);
        // --- phase close; counted vmcnt at slot-consumption boundaries ---
        if (mh == 1) {
          if (ks == 0) {
            if (stg) {
              if constexpr (BM == 256) asm volatile("s_waitcnt vmcnt(4)" ::: "memory");
              else                     asm volatile("s_waitcnt vmcnt(3)" ::: "memory");
            } else {
              asm volatile("s_waitcnt vmcnt(0)" ::: "memory");
            }
          } else if (stg) {
            if constexpr (BM == 256) asm volatile("s_waitcnt vmcnt(4)" ::: "memory");
            else                     asm volatile("s_waitcnt vmcnt(3)" ::: "memory");
          }
        }
        __builtin_amdgcn_s_barrier();
      }
    }
  }

  // ---- epilogues ----
  if constexpr (MODE == 0) {
    const int sel = bn >> 10;               // 0=Q 1=K 2=V
    if (sel < 2) {
      const float* bp = sel ? b1 : b0;
      u16* o = sel ? (u16*)o1 : (u16*)o0;
#pragma unroll
      for (int nt = 0; nt < 4; ++nt) {
        int col = (bn + wn * 64 + nt * 16 + lr) & 1023;
        float bv = bp[col];
#pragma unroll
        for (int mh = 0; mh < 2; ++mh)
#pragma unroll
          for (int mt = 0; mt < MT; ++mt) {
            int grow0 = bm + wm * (BM / 2) + mh * (BM / 4) + mt * 16 + lg * 4;
#pragma unroll
            for (int r = 0; r < 4; ++r)
              o[(size_t)(grow0 + r) * 1024 + col] = f2bf(acc[mh * MT + mt][nt][r] + bv);
          }
      }
    } else {
      // V: transpose tile through LDS (swizzled, conflict-free), 16B stores.
      u16* T = lds;                          // 256 x 256 u16 = 128 KB (reuse)
      const int col0 = bn - 2048;
      const int batch = bm >> 11;
      const int sbase = bm & 2047;
#pragma unroll
      for (int nt = 0; nt < 4; ++nt) {
        int col = wn * 64 + nt * 16 + lr;
        float bv = b2[col0 + col];
#pragma unroll
        for (int mh = 0; mh < 2; ++mh)
#pragma unroll
          for (int mt = 0; mt < MT; ++mt) {
            int row0 = wm * (BM / 2) + mh * (BM / 4) + mt * 16 + lg * 4;
#pragma unroll
            for (int r = 0; r < 4; ++r) {
              int row = row0 + r;
              T[row * 256 + (col ^ (((row >> 2) & 7) << 3))] = f2bf(acc[mh * MT + mt][nt][r] + bv);
            }
          }
      }
      __syncthreads();
      u16* o = (u16*)o2 + ((size_t)batch * 1024 + col0) * 2048 + sbase;
#pragma unroll
      for (int it = 0; it < 16; ++it) {
        int col = wv * 32 + (lane >> 2) + (it & 1) * 16;
        int s0 = ((it >> 1) * 4 + (lane & 3)) * 8;
        union { u16 u[8]; uint4 v; } pk;
#pragma unroll
        for (int k = 0; k < 8; ++k) {
          int row = s0 + k;
          pk.u[k] = T[row * 256 + (col ^ (((row >> 2) & 7) << 3))];
        }
        *(uint4*)(o + (size_t)col * 2048 + s0) = pk.v;
      }
    }
  } else if constexpr (MODE == 2) {
    u16* P = (u16*)o0 + (size_t)2048 * 2048 * bz;
    float psum[2 * MT][4];
#pragma unroll
    for (int i = 0; i < 2 * MT; ++i)
#pragma unroll
      for (int r = 0; r < 4; ++r) psum[i][r] = 0.0f;
#pragma unroll
    for (int nt = 0; nt < 4; ++nt) {
      int gcol = bn + wn * 64 + nt * 16 + lr;
#pragma unroll
      for (int i = 0; i < 2 * MT; ++i) {
        int grow0 = bm + wm * (BM / 2) + (i / MT) * (BM / 4) + (i % MT) * 16 + lg * 4;
#pragma unroll
        for (int r = 0; r < 4; ++r) {
          float e = __expf(acc[i][nt][r] * 0.03125f);
          P[(size_t)(grow0 + r) * 2048 + gcol] = f2bf(e);
          psum[i][r] += e;
        }
      }
    }
#pragma unroll
    for (int i = 0; i < 2 * MT; ++i)
#pragma unroll
      for (int r = 0; r < 4; ++r) {
#pragma unroll
        for (int off = 1; off < 16; off <<= 1)
          psum[i][r] += __shfl_xor(psum[i][r], off);
      }
    if (lr == 0) {
#pragma unroll
      for (int i = 0; i < 2 * MT; ++i) {
        int grow0 = bm + wm * (BM / 2) + (i / MT) * (BM / 4) + (i % MT) * 16 + lg * 4;
#pragma unroll
        for (int r = 0; r < 4; ++r)
          atomicAdd(&lsum[bz * 2048 + grow0 + r], psum[i][r]);
      }
    }
  } else {  // MODE 3
    float* o = (float*)o0;
#pragma unroll
    for (int i = 0; i < 2 * MT; ++i) {
      int grow0 = bm + wm * (BM / 2) + (i / MT) * (BM / 4) + (i % MT) * 16 + lg * 4;
      float inv[4];
#pragma unroll
      for (int r = 0; r < 4; ++r) inv[r] = 1.0f / lsum[grow0 + r];
#pragma unroll
      for (int nt = 0; nt < 4; ++nt) {
        int gcol = bn + wn * 64 + nt * 16 + lr;
#pragma unroll
        for (int r = 0; r < 4; ++r)
          o[(size_t)(grow0 + r) * 1024 + gcol] = acc[i][nt][r] * inv[r];
      }
    }
  }
}

// ---- launch ----------------------------------------------------------------

extern "C" void kernel_launch(void* const* d_in, const int* in_sizes, int n_in,
                              void* d_out, int out_size, void* d_ws, size_t ws_size,
                              hipStream_t stream) {
  const float* x  = (const float*)d_in[0];
  const float* Wq = (const float*)d_in[1];
  const float* bq = (const float*)d_in[2];
  const float* Wk = (const float*)d_in[3];
  const float* bk = (const float*)d_in[4];
  const float* Wv = (const float*)d_in[5];
  const float* bv = (const float*)d_in[6];
  float* out = (float*)d_out;

  char* ws = (char*)d_ws;
  u16*   xb   = (u16*)  (ws + ((size_t)0  << 20)); // 16 MB  x bf16 [8192][1024]
  u16*   wcat = (u16*)  (ws + ((size_t)16 << 20)); //  6 MB  [Wq;Wk;Wv] bf16
  float* lvec = (float*)(ws + ((size_t)23 << 20)); // 32 KB  row sums [8192]
  u16*   qb   = (u16*)  (ws + ((size_t)24 << 20)); // 16 MB  Q  [b][s][o]
  u16*   kb   = (u16*)  (ws + ((size_t)40 << 20)); // 16 MB  K  [b][s][o]
  u16*   vtb  = (u16*)  (ws + ((size_t)56 << 20)); // 16 MB  Vt [b][o][s]
  u16*   Pb   = (u16*)  (ws + ((size_t)72 << 20)); // 32 MB  P bf16 (unnorm exp)

  hipFuncSetAttribute((const void*)&gemm8<0, 256>,
                      hipFuncAttributeMaxDynamicSharedMemorySize, 131072);
  hipFuncSetAttribute((const void*)&gemm8<2, 256>,
                      hipFuncAttributeMaxDynamicSharedMemorySize, 131072);
  hipFuncSetAttribute((const void*)&gemm8<3, 128>,
                      hipFuncAttributeMaxDynamicSharedMemorySize, 98304);

  hipMemsetAsync(lvec, 0, 8192 * sizeof(float), stream);
  cvt_all<<<dim3(5632), dim3(256), 0, stream>>>(x, Wq, Wk, Wv, xb, wcat);

  // fused QKV projection: [8192x1024] x [3072x1024]^T (+bias, V transposed)
  gemm8<0, 256><<<dim3(32, 12, 1), dim3(512), 131072, stream>>>(
      xb, wcat, bq, bk, bv, qb, kb, vtb, nullptr, 1024, 1024, 16, 0, 0);

  // P = exp(Q K^T / 32) bf16 (per batch 2048x2048, K=1024), row sums -> lvec
  gemm8<2, 256><<<dim3(8, 8, 4), dim3(512), 131072, stream>>>(
      qb, kb, nullptr, nullptr, nullptr, Pb, nullptr, nullptr, lvec,
      1024, 1024, 16, (long)2048 * 1024, (long)2048 * 1024);

  // O = (P * Vt^T) / l  (batch folded into M: [8192x2048] x Vt[b]^T, K=2048)
  gemm8<3, 128><<<dim3(64, 4, 1), dim3(512), 98304, stream>>>(
      Pb, vtb, nullptr, nullptr, nullptr, out, nullptr, nullptr, lvec,
      2048, 2048, 32, 0, (long)1024 * 2048);
}

// Round 7
// 263.491 us; speedup vs baseline: 1.0235x; 1.0235x over previous
//
#include <hip/hip_runtime.h>
#include <hip/hip_bf16.h>

typedef __attribute__((ext_vector_type(8))) short bf16x8;
typedef __attribute__((ext_vector_type(4))) float f32x4;
typedef unsigned short u16;
typedef unsigned int u32;

// ---- helpers ---------------------------------------------------------------

__device__ __forceinline__ u16 f2bf(float f) {
  union { float f; u32 u; } v; v.f = f;
  u32 r = v.u + 0x7FFFu + ((v.u >> 16) & 1u);   // round-to-nearest-even
  return (u16)(r >> 16);
}

__device__ __forceinline__ void gload_lds16(const u16* g, u16* l) {
  __builtin_amdgcn_global_load_lds(
      (const __attribute__((address_space(1))) u32*)(const void*)g,
      (__attribute__((address_space(3))) u32*)(void*)l, 16, 0, 0);
}

// ---- merged fp32 -> bf16 conversion + lvec zeroing (one launch) ------------

__global__ __launch_bounds__(256) void cvt_all(const float* __restrict__ x,
                                               const float* __restrict__ wq,
                                               const float* __restrict__ wk,
                                               const float* __restrict__ wv,
                                               u16* __restrict__ xb,
                                               u16* __restrict__ wcat,
                                               float* __restrict__ lvec) {
  const int bid = blockIdx.x;
  if (bid == 5632) {                       // zero the 8192-float row-sum vec
    float4 z = make_float4(0.f, 0.f, 0.f, 0.f);
#pragma unroll
    for (int j = 0; j < 8; ++j)
      *(float4*)(lvec + (j * 256 + threadIdx.x) * 4) = z;
    return;
  }
  const float* src; u16* dst; size_t base;
  if (bid < 4096) { src = x; dst = xb; base = (size_t)bid * 2048; }
  else {
    int w = bid - 4096, s = w >> 9;
    src = (s == 0) ? wq : ((s == 1) ? wk : wv);
    dst = wcat + (size_t)s * 1048576;
    base = (size_t)(w & 511) * 2048;
  }
  size_t i = base + (size_t)threadIdx.x * 8;
  const float4* p = (const float4*)(src + i);
  float4 a = p[0], b = p[1];
  union { u16 u[8]; uint4 v; } r;
  r.u[0] = f2bf(a.x); r.u[1] = f2bf(a.y); r.u[2] = f2bf(a.z); r.u[3] = f2bf(a.w);
  r.u[4] = f2bf(b.x); r.u[5] = f2bf(b.y); r.u[6] = f2bf(b.z); r.u[7] = f2bf(b.w);
  *(uint4*)(dst + i) = r.v;
}

// ---- 128x128-tile B^T GEMM (R2 engine: proven 0-conflict, multi-block/CU) --
// C[bm..][bn..] = A[M x K, row-major, lda] * B[N x K, row-major, ldb]^T
// 4 waves (2x2 of 64x64), BK=64, global_load_lds w16, linear LDS dest +
// XOR-swizzled global source (rule #21) so ds_read_b128 is ~2-way.
// MODE 0: fused QKV projection. B = [Wq;Wk;Wv] (3072x1024); bias by column
//         range. V-blocks transpose the tile through the (reused) 32 KB LDS
//         (swizzle col^(((row>>2)&7)<<3), <=2-way both sides) and store
//         Vt[b][o][s] as coalesced 16B chunks along s.
// MODE 2: P = exp(QK^T/32) bf16 (ld 2048) + row-sum atomics into lsum.
// MODE 3: O = (P * Vt^T) / lsum, fp32 out; batch folded into M (8192 rows).

template<int MODE>
__global__ __launch_bounds__(256) void gemm128(
    const u16* __restrict__ A, const u16* __restrict__ B,
    const float* __restrict__ b0, const float* __restrict__ b1,
    const float* __restrict__ b2,
    void* __restrict__ o0, void* __restrict__ o1, void* __restrict__ o2,
    float* __restrict__ lsum, int lda, int ldb, int nkt,
    long Abat, long Bbat) {
  __shared__ u16 smem[16384];             // As[0:8192) Bs[8192:16384); T=all
  u16* As = smem;
  u16* Bs = smem + 8192;
  const int tid = threadIdx.x;
  const int lane = tid & 63, wv = tid >> 6;
  const int lr = lane & 15, lg = lane >> 4;
  const int wm = (wv >> 1) * 64, wn = (wv & 1) * 64;
  const int bm = blockIdx.x * 128, bn = blockIdx.y * 128;
  const int bz = blockIdx.z;

  const u16* Ab; const u16* Bb;
  if constexpr (MODE == 3) { Ab = A; Bb = B + (size_t)Bbat * (bm >> 11); }
  else { Ab = A + (size_t)Abat * bz; Bb = B + (size_t)Bbat * bz; }

  f32x4 acc[4][4];
#pragma unroll
  for (int i = 0; i < 4; ++i)
#pragma unroll
    for (int j = 0; j < 4; ++j) acc[i][j] = (f32x4)0.0f;

  for (int kt = 0; kt < nkt; ++kt) {
    const int k0 = kt * 64;
#pragma unroll
    for (int i = 0; i < 4; ++i) {           // stage A and B tiles (swizzled src)
      int id = i * 256 + tid;
      int row = id >> 3, c = id & 7;
      int cg = c ^ (row & 7);
      gload_lds16(Ab + (size_t)(bm + row) * lda + k0 + cg * 8, As + id * 8);
      gload_lds16(Bb + (size_t)(bn + row) * ldb + k0 + cg * 8, Bs + id * 8);
    }
    __syncthreads();
#pragma unroll
    for (int kk = 0; kk < 2; ++kk) {
      bf16x8 a[4], b[4];
#pragma unroll
      for (int mt = 0; mt < 4; ++mt) {
        int row = wm + mt * 16 + lr;
        int kc = (kk * 4 + lg) ^ (row & 7);
        a[mt] = *(const bf16x8*)(As + row * 64 + kc * 8);
      }
#pragma unroll
      for (int nt = 0; nt < 4; ++nt) {
        int row = wn + nt * 16 + lr;
        int kc = (kk * 4 + lg) ^ (row & 7);
        b[nt] = *(const bf16x8*)(Bs + row * 64 + kc * 8);
      }
#pragma unroll
      for (int mt = 0; mt < 4; ++mt)
#pragma unroll
        for (int nt = 0; nt < 4; ++nt)
          acc[mt][nt] = __builtin_amdgcn_mfma_f32_16x16x32_bf16(a[mt], b[nt], acc[mt][nt], 0, 0, 0);
    }
    __syncthreads();
  }

  // ---- epilogues ----
  if constexpr (MODE == 0) {
    const int sel = bn >> 10;               // 0=Q 1=K 2=V
    if (sel < 2) {
      const float* bp = sel ? b1 : b0;
      u16* o = sel ? (u16*)o1 : (u16*)o0;
#pragma unroll
      for (int nt = 0; nt < 4; ++nt) {
        int col = (bn + wn + nt * 16 + lr) & 1023;
        float bv = bp[col];
#pragma unroll
        for (int mt = 0; mt < 4; ++mt) {
          int grow0 = bm + wm + mt * 16 + lg * 4;
#pragma unroll
          for (int r = 0; r < 4; ++r)
            o[(size_t)(grow0 + r) * 1024 + col] = f2bf(acc[mt][nt][r] + bv);
        }
      }
    } else {
      // V: transpose tile through LDS (reuses As/Bs: 128x128 u16 = 32 KB).
      u16* T = smem;
      const int col0 = bn - 2048;           // V output col base (0..896)
      const int batch = bm >> 11;
      const int sbase = bm & 2047;
#pragma unroll
      for (int nt = 0; nt < 4; ++nt) {
        int col = wn + nt * 16 + lr;        // 0..127 within tile
        float bv = b2[col0 + col];
#pragma unroll
        for (int mt = 0; mt < 4; ++mt) {
          int row0 = wm + mt * 16 + lg * 4;
#pragma unroll
          for (int r = 0; r < 4; ++r) {
            int row = row0 + r;
            T[row * 128 + (col ^ (((row >> 2) & 7) << 3))] = f2bf(acc[mt][nt][r] + bv);
          }
        }
      }
      __syncthreads();
      u16* o = (u16*)o2 + ((size_t)batch * 1024 + col0) * 2048 + sbase;
#pragma unroll
      for (int it = 0; it < 8; ++it) {
        int col = wv * 32 + (lane >> 2) + (it & 1) * 16;
        int s0 = ((it >> 1) * 4 + (lane & 3)) * 8;
        union { u16 u[8]; uint4 v; } pk;
#pragma unroll
        for (int k = 0; k < 8; ++k) {
          int row = s0 + k;
          pk.u[k] = T[row * 128 + (col ^ (((row >> 2) & 7) << 3))];
        }
        *(uint4*)(o + (size_t)col * 2048 + s0) = pk.v;
      }
    }
  } else if constexpr (MODE == 2) {
    u16* P = (u16*)o0 + (size_t)2048 * 2048 * bz;
    float psum[4][4];
#pragma unroll
    for (int mt = 0; mt < 4; ++mt)
#pragma unroll
      for (int r = 0; r < 4; ++r) psum[mt][r] = 0.0f;
#pragma unroll
    for (int nt = 0; nt < 4; ++nt) {
      int gcol = bn + wn + nt * 16 + lr;
#pragma unroll
      for (int mt = 0; mt < 4; ++mt) {
        int grow0 = bm + wm + mt * 16 + lg * 4;
#pragma unroll
        for (int r = 0; r < 4; ++r) {
          float e = __expf(acc[mt][nt][r] * 0.03125f);
          P[(size_t)(grow0 + r) * 2048 + gcol] = f2bf(e);
          psum[mt][r] += e;
        }
      }
    }
#pragma unroll
    for (int mt = 0; mt < 4; ++mt)
#pragma unroll
      for (int r = 0; r < 4; ++r) {
#pragma unroll
        for (int off = 1; off < 16; off <<= 1)
          psum[mt][r] += __shfl_xor(psum[mt][r], off);
      }
    if (lr == 0) {
#pragma unroll
      for (int mt = 0; mt < 4; ++mt) {
        int grow0 = bm + wm + mt * 16 + lg * 4;
#pragma unroll
        for (int r = 0; r < 4; ++r)
          atomicAdd(&lsum[bz * 2048 + grow0 + r], psum[mt][r]);
      }
    }
  } else {  // MODE 3
    float* o = (float*)o0;
#pragma unroll
    for (int mt = 0; mt < 4; ++mt) {
      int grow0 = bm + wm + mt * 16 + lg * 4;
      float inv[4];
#pragma unroll
      for (int r = 0; r < 4; ++r) inv[r] = 1.0f / lsum[grow0 + r];
#pragma unroll
      for (int nt = 0; nt < 4; ++nt) {
        int gcol = bn + wn + nt * 16 + lr;
#pragma unroll
        for (int r = 0; r < 4; ++r)
          o[(size_t)(grow0 + r) * 1024 + gcol] = acc[mt][nt][r] * inv[r];
      }
    }
  }
}

// ---- launch ----------------------------------------------------------------

extern "C" void kernel_launch(void* const* d_in, const int* in_sizes, int n_in,
                              void* d_out, int out_size, void* d_ws, size_t ws_size,
                              hipStream_t stream) {
  const float* x  = (const float*)d_in[0];
  const float* Wq = (const float*)d_in[1];
  const float* bq = (const float*)d_in[2];
  const float* Wk = (const float*)d_in[3];
  const float* bk = (const float*)d_in[4];
  const float* Wv = (const float*)d_in[5];
  const float* bv = (const float*)d_in[6];
  float* out = (float*)d_out;

  char* ws = (char*)d_ws;
  u16*   xb   = (u16*)  (ws + ((size_t)0  << 20)); // 16 MB  x bf16 [8192][1024]
  u16*   wcat = (u16*)  (ws + ((size_t)16 << 20)); //  6 MB  [Wq;Wk;Wv] bf16
  float* lvec = (float*)(ws + ((size_t)23 << 20)); // 32 KB  row sums [8192]
  u16*   qb   = (u16*)  (ws + ((size_t)24 << 20)); // 16 MB  Q  [b][s][o]
  u16*   kb   = (u16*)  (ws + ((size_t)40 << 20)); // 16 MB  K  [b][s][o]
  u16*   vtb  = (u16*)  (ws + ((size_t)56 << 20)); // 16 MB  Vt [b][o][s]
  u16*   Pb   = (u16*)  (ws + ((size_t)72 << 20)); // 32 MB  P bf16 (unnorm exp)

  // conversions + lvec zeroing (one launch)
  cvt_all<<<dim3(5633), dim3(256), 0, stream>>>(x, Wq, Wk, Wv, xb, wcat, lvec);

  // fused QKV projection: [8192x1024] x [3072x1024]^T (+bias, V transposed)
  gemm128<0><<<dim3(64, 24, 1), dim3(256), 0, stream>>>(
      xb, wcat, bq, bk, bv, qb, kb, vtb, nullptr, 1024, 1024, 16, 0, 0);

  // P = exp(Q K^T / 32) bf16 (per batch 2048x2048, K=1024), row sums -> lvec
  gemm128<2><<<dim3(16, 16, 4), dim3(256), 0, stream>>>(
      qb, kb, nullptr, nullptr, nullptr, Pb, nullptr, nullptr, lvec,
      1024, 1024, 16, (long)2048 * 1024, (long)2048 * 1024);

  // O = (P * Vt^T) / l  (batch folded into M: [8192x2048] x Vt[b]^T, K=2048)
  gemm128<3><<<dim3(64, 8, 1), dim3(256), 0, stream>>>(
      Pb, vtb, nullptr, nullptr, nullptr, out, nullptr, nullptr, lvec,
      2048, 2048, 32, 0, (long)1024 * 2048);
}

// Round 8
// 246.109 us; speedup vs baseline: 1.0958x; 1.0706x over previous
//
#include <hip/hip_runtime.h>
#include <hip/hip_bf16.h>

typedef __attribute__((ext_vector_type(8))) short bf16x8;
typedef __attribute__((ext_vector_type(4))) float f32x4;
typedef unsigned short u16;
typedef unsigned int u32;

// ---- helpers ---------------------------------------------------------------

__device__ __forceinline__ u16 f2bf(float f) {
  union { float f; u32 u; } v; v.f = f;
  u32 r = v.u + 0x7FFFu + ((v.u >> 16) & 1u);   // round-to-nearest-even
  return (u16)(r >> 16);
}

__device__ __forceinline__ void gload_lds16(const u16* g, u16* l) {
  __builtin_amdgcn_global_load_lds(
      (const __attribute__((address_space(1))) u32*)(const void*)g,
      (__attribute__((address_space(3))) u32*)(void*)l, 16, 0, 0);
}

// ---- merged fp32 -> bf16 conversion + lvec zeroing (one launch) ------------

__global__ __launch_bounds__(256) void cvt_all(const float* __restrict__ x,
                                               const float* __restrict__ wq,
                                               const float* __restrict__ wk,
                                               const float* __restrict__ wv,
                                               u16* __restrict__ xb,
                                               u16* __restrict__ wcat,
                                               float* __restrict__ lvec) {
  const int bid = blockIdx.x;
  if (bid == 5632) {                       // zero the 8192-float row-sum vec
    float4 z = make_float4(0.f, 0.f, 0.f, 0.f);
#pragma unroll
    for (int j = 0; j < 8; ++j)
      *(float4*)(lvec + (j * 256 + threadIdx.x) * 4) = z;
    return;
  }
  const float* src; u16* dst; size_t base;
  if (bid < 4096) { src = x; dst = xb; base = (size_t)bid * 2048; }
  else {
    int w = bid - 4096, s = w >> 9;
    src = (s == 0) ? wq : ((s == 1) ? wk : wv);
    dst = wcat + (size_t)s * 1048576;
    base = (size_t)(w & 511) * 2048;
  }
  size_t i = base + (size_t)threadIdx.x * 8;
  const float4* p = (const float4*)(src + i);
  float4 a = p[0], b = p[1];
  union { u16 u[8]; uint4 v; } r;
  r.u[0] = f2bf(a.x); r.u[1] = f2bf(a.y); r.u[2] = f2bf(a.z); r.u[3] = f2bf(a.w);
  r.u[4] = f2bf(b.x); r.u[5] = f2bf(b.y); r.u[6] = f2bf(b.z); r.u[7] = f2bf(b.w);
  *(uint4*)(dst + i) = r.v;
}

// ---- QKV: 128x128-tile B^T GEMM (R3-measured config: 67 us) ----------------
// 4 waves (2x2 of 64x64), BK=64, global_load_lds w16, linear LDS dest +
// XOR-swizzled global source so ds_read_b128 is ~2-way (0 conflicts).
// B = [Wq;Wk;Wv] (3072x1024); bias by column range. V-blocks write Vt[b][o][s]
// via scattered uint2 (measured FASTER than the LDS-transpose variant).

__global__ __launch_bounds__(256) void gemm_qkv(
    const u16* __restrict__ A, const u16* __restrict__ B,
    const float* __restrict__ b0, const float* __restrict__ b1,
    const float* __restrict__ b2,
    u16* __restrict__ oq, u16* __restrict__ ok, u16* __restrict__ ovt) {
  __shared__ u16 As[8192];
  __shared__ u16 Bs[8192];
  const int tid = threadIdx.x;
  const int lane = tid & 63, wv = tid >> 6;
  const int lr = lane & 15, lg = lane >> 4;
  const int wm = (wv >> 1) * 64, wn = (wv & 1) * 64;
  const int bm = blockIdx.x * 128, bn = blockIdx.y * 128;

  f32x4 acc[4][4];
#pragma unroll
  for (int i = 0; i < 4; ++i)
#pragma unroll
    for (int j = 0; j < 4; ++j) acc[i][j] = (f32x4)0.0f;

  for (int kt = 0; kt < 16; ++kt) {
    const int k0 = kt * 64;
#pragma unroll
    for (int i = 0; i < 4; ++i) {           // stage A and B tiles (swizzled src)
      int id = i * 256 + tid;
      int row = id >> 3, c = id & 7;
      int cg = c ^ (row & 7);
      gload_lds16(A + (size_t)(bm + row) * 1024 + k0 + cg * 8, As + id * 8);
      gload_lds16(B + (size_t)(bn + row) * 1024 + k0 + cg * 8, Bs + id * 8);
    }
    __syncthreads();
#pragma unroll
    for (int kk = 0; kk < 2; ++kk) {
      bf16x8 a[4], b[4];
#pragma unroll
      for (int mt = 0; mt < 4; ++mt) {
        int row = wm + mt * 16 + lr;
        int kc = (kk * 4 + lg) ^ (row & 7);
        a[mt] = *(const bf16x8*)(As + row * 64 + kc * 8);
      }
#pragma unroll
      for (int nt = 0; nt < 4; ++nt) {
        int row = wn + nt * 16 + lr;
        int kc = (kk * 4 + lg) ^ (row & 7);
        b[nt] = *(const bf16x8*)(Bs + row * 64 + kc * 8);
      }
#pragma unroll
      for (int mt = 0; mt < 4; ++mt)
#pragma unroll
        for (int nt = 0; nt < 4; ++nt)
          acc[mt][nt] = __builtin_amdgcn_mfma_f32_16x16x32_bf16(a[mt], b[nt], acc[mt][nt], 0, 0, 0);
    }
    __syncthreads();
  }

  const int sel = bn >> 10;               // 0=Q 1=K 2=V
  const float* bp = (sel == 0) ? b0 : ((sel == 1) ? b1 : b2);
#pragma unroll
  for (int nt = 0; nt < 4; ++nt) {
    int col = (bn + wn + nt * 16 + lr) & 1023;
    float bv = bp[col];
#pragma unroll
    for (int mt = 0; mt < 4; ++mt) {
      int grow0 = bm + wm + mt * 16 + lg * 4;
      if (sel < 2) {
        u16* o = sel ? ok : oq;
#pragma unroll
        for (int r = 0; r < 4; ++r)
          o[(size_t)(grow0 + r) * 1024 + col] = f2bf(acc[mt][nt][r] + bv);
      } else {
        int batch = grow0 >> 11, s = grow0 & 2047;
        union { u16 u[4]; uint2 v; } pk;
#pragma unroll
        for (int r = 0; r < 4; ++r) pk.u[r] = f2bf(acc[mt][nt][r] + bv);
        *(uint2*)(ovt + (((size_t)(batch * 1024 + col)) << 11) + s) = pk.v;
      }
    }
  }
}

// ---- S / PV: pipelined B^T GEMM (R5-measured engine) -----------------------
// BM x 256 tile, 8 waves (2 x 4; wave owns BM/2 x 64), BK=64, dynamic LDS
// 2 x (A BMx64 + B 256x64) bf16, issue-early / drain-late double buffer.
// MODE 2: P = exp(QK^T/32) bf16 + row-sum atomics into lsum.
// MODE 3: O = (P * Vt^T) / lsum, fp32 out; batch folded into M.

template<int MODE, int BM, int BN>
__global__ __launch_bounds__(512, 2) void gemm_pipe(
    const u16* __restrict__ A, const u16* __restrict__ B,
    void* __restrict__ o0, float* __restrict__ lsum,
    int lda, int ldb, int nkt, long Abat, long Bbat) {
  extern __shared__ u16 lds[];
  constexpr int NMT = BM / 32;
  constexpr int ANL = BM / 64;
  constexpr int BNL = BN / 64;
  constexpr int ASZ = BM * 64, BSZ = BN * 64;

  const int tid = threadIdx.x;
  const int lane = tid & 63, wv = tid >> 6;
  const int lr = lane & 15, lg = lane >> 4;
  const int wm = wv >> 2, wn = wv & 3;
  const int bm = blockIdx.x * BM, bn = blockIdx.y * BN;
  const int bz = blockIdx.z;

  const u16* Ab; const u16* Bb;
  if constexpr (MODE == 3) { Ab = A; Bb = B + (size_t)Bbat * (bm >> 11); }
  else { Ab = A + (size_t)Abat * bz; Bb = B + (size_t)Bbat * bz; }

  f32x4 acc[NMT][4];
#pragma unroll
  for (int i = 0; i < NMT; ++i)
#pragma unroll
    for (int j = 0; j < 4; ++j) acc[i][j] = (f32x4)0.0f;

  auto stage = [&](int kt, int buf) {
    u16* As = lds + buf * (ASZ + BSZ);
    u16* Bs = As + ASZ;
    const int k0 = kt * 64;
#pragma unroll
    for (int j = 0; j < ANL; ++j) {
      int id = j * 512 + tid, row = id >> 3, c = id & 7, cg = c ^ (row & 7);
      gload_lds16(Ab + (size_t)(bm + row) * lda + k0 + cg * 8, As + id * 8);
    }
#pragma unroll
    for (int j = 0; j < BNL; ++j) {
      int id = j * 512 + tid, row = id >> 3, c = id & 7, cg = c ^ (row & 7);
      gload_lds16(Bb + (size_t)(bn + row) * ldb + k0 + cg * 8, Bs + id * 8);
    }
  };

  stage(0, 0);
  __syncthreads();

  for (int kt = 0; kt < nkt; ++kt) {
    if (kt + 1 < nkt) stage(kt + 1, (kt + 1) & 1);   // issue-early
    __builtin_amdgcn_sched_barrier(0);               // pin issue above compute
    const u16* As = lds + (kt & 1) * (ASZ + BSZ);
    const u16* Bs = As + ASZ;
#pragma unroll
    for (int kk = 0; kk < 2; ++kk) {
      bf16x8 a[NMT], b[4];
#pragma unroll
      for (int mt = 0; mt < NMT; ++mt) {
        int row = wm * (BM / 2) + mt * 16 + lr;
        int kc = (kk * 4 + lg) ^ (row & 7);
        a[mt] = *(const bf16x8*)(As + row * 64 + kc * 8);
      }
#pragma unroll
      for (int nt = 0; nt < 4; ++nt) {
        int row = wn * 64 + nt * 16 + lr;
        int kc = (kk * 4 + lg) ^ (row & 7);
        b[nt] = *(const bf16x8*)(Bs + row * 64 + kc * 8);
      }
#pragma unroll
      for (int mt = 0; mt < NMT; ++mt)
#pragma unroll
        for (int nt = 0; nt < 4; ++nt)
          acc[mt][nt] = __builtin_amdgcn_mfma_f32_16x16x32_bf16(a[mt], b[nt], acc[mt][nt], 0, 0, 0);
    }
    __syncthreads();                                  // drain-late (loads landed)
  }

  if constexpr (MODE == 2) {
    u16* P = (u16*)o0 + (size_t)2048 * 2048 * bz;
    float psum[NMT][4];
#pragma unroll
    for (int mt = 0; mt < NMT; ++mt)
#pragma unroll
      for (int r = 0; r < 4; ++r) psum[mt][r] = 0.0f;
#pragma unroll
    for (int nt = 0; nt < 4; ++nt) {
      int gcol = bn + wn * 64 + nt * 16 + lr;
#pragma unroll
      for (int mt = 0; mt < NMT; ++mt) {
        int grow0 = bm + wm * (BM / 2) + mt * 16 + lg * 4;
#pragma unroll
        for (int r = 0; r < 4; ++r) {
          float e = __expf(acc[mt][nt][r] * 0.03125f);
          P[(size_t)(grow0 + r) * 2048 + gcol] = f2bf(e);
          psum[mt][r] += e;
        }
      }
    }
#pragma unroll
    for (int mt = 0; mt < NMT; ++mt)
#pragma unroll
      for (int r = 0; r < 4; ++r) {
#pragma unroll
        for (int off = 1; off < 16; off <<= 1)
          psum[mt][r] += __shfl_xor(psum[mt][r], off);
      }
    if (lr == 0) {
#pragma unroll
      for (int mt = 0; mt < NMT; ++mt) {
        int grow0 = bm + wm * (BM / 2) + mt * 16 + lg * 4;
#pragma unroll
        for (int r = 0; r < 4; ++r)
          atomicAdd(&lsum[bz * 2048 + grow0 + r], psum[mt][r]);
      }
    }
  } else {  // MODE 3
    float* o = (float*)o0;
#pragma unroll
    for (int mt = 0; mt < NMT; ++mt) {
      int grow0 = bm + wm * (BM / 2) + mt * 16 + lg * 4;
      float inv[4];
#pragma unroll
      for (int r = 0; r < 4; ++r) inv[r] = 1.0f / lsum[grow0 + r];
#pragma unroll
      for (int nt = 0; nt < 4; ++nt) {
        int gcol = bn + wn * 64 + nt * 16 + lr;
#pragma unroll
        for (int r = 0; r < 4; ++r)
          o[(size_t)(grow0 + r) * 1024 + gcol] = acc[mt][nt][r] * inv[r];
      }
    }
  }
}

// ---- launch ----------------------------------------------------------------

extern "C" void kernel_launch(void* const* d_in, const int* in_sizes, int n_in,
                              void* d_out, int out_size, void* d_ws, size_t ws_size,
                              hipStream_t stream) {
  const float* x  = (const float*)d_in[0];
  const float* Wq = (const float*)d_in[1];
  const float* bq = (const float*)d_in[2];
  const float* Wk = (const float*)d_in[3];
  const float* bk = (const float*)d_in[4];
  const float* Wv = (const float*)d_in[5];
  const float* bv = (const float*)d_in[6];
  float* out = (float*)d_out;

  char* ws = (char*)d_ws;
  u16*   xb   = (u16*)  (ws + ((size_t)0  << 20)); // 16 MB  x bf16 [8192][1024]
  u16*   wcat = (u16*)  (ws + ((size_t)16 << 20)); //  6 MB  [Wq;Wk;Wv] bf16
  float* lvec = (float*)(ws + ((size_t)23 << 20)); // 32 KB  row sums [8192]
  u16*   qb   = (u16*)  (ws + ((size_t)24 << 20)); // 16 MB  Q  [b][s][o]
  u16*   kb   = (u16*)  (ws + ((size_t)40 << 20)); // 16 MB  K  [b][s][o]
  u16*   vtb  = (u16*)  (ws + ((size_t)56 << 20)); // 16 MB  Vt [b][o][s]
  u16*   Pb   = (u16*)  (ws + ((size_t)72 << 20)); // 32 MB  P bf16 (unnorm exp)

  hipFuncSetAttribute((const void*)&gemm_pipe<2, 256, 256>,
                      hipFuncAttributeMaxDynamicSharedMemorySize, 131072);
  hipFuncSetAttribute((const void*)&gemm_pipe<3, 128, 256>,
                      hipFuncAttributeMaxDynamicSharedMemorySize, 98304);

  // conversions + lvec zeroing (one launch)
  cvt_all<<<dim3(5633), dim3(256), 0, stream>>>(x, Wq, Wk, Wv, xb, wcat, lvec);

  // fused QKV projection: [8192x1024] x [3072x1024]^T (+bias, V transposed)
  gemm_qkv<<<dim3(64, 24, 1), dim3(256), 0, stream>>>(
      xb, wcat, bq, bk, bv, qb, kb, vtb);

  // P = exp(Q K^T / 32) bf16 (per batch 2048x2048, K=1024), row sums -> lvec
  gemm_pipe<2, 256, 256><<<dim3(8, 8, 4), dim3(512), 131072, stream>>>(
      qb, kb, Pb, lvec, 1024, 1024, 16, (long)2048 * 1024, (long)2048 * 1024);

  // O = (P * Vt^T) / l  (batch folded into M: [8192x2048] x Vt[b]^T, K=2048)
  gemm_pipe<3, 128, 256><<<dim3(64, 4, 1), dim3(512), 98304, stream>>>(
      Pb, vtb, out, lvec, 2048, 2048, 32, 0, (long)1024 * 2048);
}